// Round 6
// baseline (59.506 us; speedup 1.0000x reference)
//
#include <hip/hip_runtime.h>

#define S_DIM 1024
#define T_DIM 64
#define B_DIM 8
#define K_DIM 512   // KEY_DIM == QUERY_DIM
#define H_DIM 256

typedef _Float16 f16;
typedef __attribute__((ext_vector_type(4))) _Float16 f16x4;
typedef __attribute__((ext_vector_type(8))) _Float16 f16x8;
typedef __attribute__((ext_vector_type(4))) float f32x4;

__device__ __forceinline__ float fast_rcp(float x) { return __builtin_amdgcn_rcpf(x); }

// tanh(x) = 1 - 2/(e^{2x}+1); robust for all x (rcp(inf)=0)
__device__ __forceinline__ float fast_tanh(float x) {
    float e = __expf(2.0f * x);
    return 1.0f - 2.0f * fast_rcp(e + 1.0f);
}

__device__ __forceinline__ void gload16(const void* g, void* l) {
    __builtin_amdgcn_global_load_lds(
        (const __attribute__((address_space(1))) unsigned int*)g,
        (__attribute__((address_space(3))) unsigned int*)l, 16, 0, 0);
}

// One launch: key->Khi/Klo (fp16 split), query->Qhi/Qlo, Wk/Wq -> transposed fp16 WT[N][K]
__global__ __launch_bounds__(256) void convert_all(
    const float* __restrict__ key, const float* __restrict__ query,
    const float* __restrict__ Wk, const float* __restrict__ Wq,
    f16* __restrict__ Khi, f16* __restrict__ Klo,
    f16* __restrict__ Qhi, f16* __restrict__ Qlo,
    f16* __restrict__ WTk, f16* __restrict__ WTq)
{
    __shared__ float tile[64][65];
    const int tid = threadIdx.x;
    const int bid = blockIdx.x;
    if (bid < 2048) {                       // key: 4.2M elems
        const int n4 = (S_DIM * B_DIM * K_DIM) / 4;
        for (int i = bid * 256 + tid; i < n4; i += 2048 * 256) {
            float4 x = ((const float4*)key)[i];
            f16 h0 = (f16)x.x, h1 = (f16)x.y, h2 = (f16)x.z, h3 = (f16)x.w;
            f16x4 hv = {h0, h1, h2, h3};
            f16x4 lv = {(f16)(x.x - (float)h0), (f16)(x.y - (float)h1),
                        (f16)(x.z - (float)h2), (f16)(x.w - (float)h3)};
            *(f16x4*)&Khi[(size_t)i * 4] = hv;
            *(f16x4*)&Klo[(size_t)i * 4] = lv;
        }
    } else if (bid < 2304) {                // query: 262144 elems = 65536 f4
        int i = (bid - 2048) * 256 + tid;
        float4 x = ((const float4*)query)[i];
        f16 h0 = (f16)x.x, h1 = (f16)x.y, h2 = (f16)x.z, h3 = (f16)x.w;
        f16x4 hv = {h0, h1, h2, h3};
        f16x4 lv = {(f16)(x.x - (float)h0), (f16)(x.y - (float)h1),
                    (f16)(x.z - (float)h2), (f16)(x.w - (float)h3)};
        *(f16x4*)&Qhi[(size_t)i * 4] = hv;
        *(f16x4*)&Qlo[(size_t)i * 4] = lv;
    } else {                                // W transpose+convert: 64 blocks (2 mats x 32 tiles)
        int idx = bid - 2304;
        const float* W = (idx & 32) ? Wq : Wk;
        f16* WT = (idx & 32) ? WTq : WTk;
        int t32 = idx & 31;
        int k0 = (t32 >> 2) * 64, n0 = (t32 & 3) * 64;
        int c = tid & 63, r0 = tid >> 6;
#pragma unroll
        for (int i = 0; i < 16; ++i) {
            int r = r0 + i * 4;
            tile[r][c] = W[(size_t)(k0 + r) * H_DIM + n0 + c];
        }
        __syncthreads();
#pragma unroll
        for (int i = 0; i < 16; ++i) {
            int r = r0 + i * 4;
            WT[(size_t)(n0 + r) * K_DIM + k0 + c] = (f16)tile[c][r];
        }
    }
}

// P = tanh(A @ W + bias), A = Ahi+Alo (fp16 split), W as fp16 BT[N][K].
// 64x64 tile, BK=64, 4 waves (2x2, 32x32 each).
// 3-deep LDS pipeline with counted vmcnt (T3/T4): 12 loads stay in flight across barriers.
// LDS dest of global_load_lds is WAVE-UNIFORM (readfirstlane) base; HW adds lane*16.
// bid<512: key (write tk[m][h]); else query (write tq2[b][t][h]).
__global__ __launch_bounds__(256, 2) void proj_gemm_all(
    const f16* __restrict__ Khi, const f16* __restrict__ Klo,
    const f16* __restrict__ WTk, const float* __restrict__ bk, float* __restrict__ tk,
    const f16* __restrict__ Qhi, const f16* __restrict__ Qlo,
    const f16* __restrict__ WTq, const float* __restrict__ bq, float* __restrict__ tq2)
{
    __shared__ __align__(16) char smem[3][3][8192];   // [buf][Ahi,Alo,B][64 rows x 128 B]
    const int tid = threadIdx.x;
    const int lane = tid & 63, wid = tid >> 6;
    const int widu = __builtin_amdgcn_readfirstlane(wid);   // wave-uniform SGPR copy
    const int wm = (wid >> 1) * 32, wn = (wid & 1) * 32;

    const int bid = blockIdx.x;
    const bool isQ = bid >= 512;
    const int lb = isQ ? bid - 512 : bid;
    const size_t m0 = (size_t)(lb >> 2) * 64;
    const int n0 = (lb & 3) * 64;
    const f16* Ahi = isQ ? Qhi : Khi;
    const f16* Alo = isQ ? Qlo : Klo;
    const f16* BT  = isQ ? WTq : WTk;
    const float* bias = isQ ? bq : bk;
    float* P = isQ ? tq2 : tk;

    // per-lane GLOBAL source byte offsets (XOR involution on bits 4-6 by row&7);
    // LDS dest is linear: lane i lands at widu*1024 + i*16 (HW-added).
    const int o0 = wid * 1024 + (lane << 4);
    const int o1 = o0 + 4096;
    const int row0 = o0 >> 7, kb0 = (o0 & 127) ^ ((row0 & 7) << 4);
    const int row1 = o1 >> 7, kb1 = (o1 & 127) ^ ((row1 & 7) << 4);

    const char* a_hi = (const char*)(Ahi + m0 * K_DIM);
    const char* a_lo = (const char*)(Alo + m0 * K_DIM);
    const char* b_t  = (const char*)(BT + (size_t)n0 * K_DIM);

    auto STAGE = [&](int buf, int t) {
        const int kb = t * 128;   // 64 halfs per k-step
        char* d0a = &smem[buf][0][widu * 1024];
        char* d1a = d0a + 4096;
        char* d0l = &smem[buf][1][widu * 1024];
        char* d1l = d0l + 4096;
        char* d0b = &smem[buf][2][widu * 1024];
        char* d1b = d0b + 4096;
        gload16(a_hi + (size_t)row0 * 1024 + kb + kb0, d0a);
        gload16(a_hi + (size_t)row1 * 1024 + kb + kb1, d1a);
        gload16(a_lo + (size_t)row0 * 1024 + kb + kb0, d0l);
        gload16(a_lo + (size_t)row1 * 1024 + kb + kb1, d1l);
        gload16(b_t  + (size_t)row0 * 1024 + kb + kb0, d0b);
        gload16(b_t  + (size_t)row1 * 1024 + kb + kb1, d1b);
    };

    f32x4 acc[2][2] = {};
    const int fr = lane & 15, fgb = (lane >> 4) << 4;

    auto COMPUTE = [&](int buf) {
#pragma unroll
        for (int kk = 0; kk < 2; ++kk) {
            const int kbyte = kk * 64 + fgb;
            auto ld = [&](int arr, int row) -> f16x8 {
                int byt = ((row << 7) + kbyte) ^ ((row & 7) << 4);
                return *(const f16x8*)&smem[buf][arr][byt];
            };
            f16x8 ah0 = ld(0, wm + fr),      ah1 = ld(0, wm + 16 + fr);
            f16x8 al0 = ld(1, wm + fr),      al1 = ld(1, wm + 16 + fr);
            f16x8 b0  = ld(2, wn + fr),      b1  = ld(2, wn + 16 + fr);
            acc[0][0] = __builtin_amdgcn_mfma_f32_16x16x32_f16(ah0, b0, acc[0][0], 0, 0, 0);
            acc[0][1] = __builtin_amdgcn_mfma_f32_16x16x32_f16(ah0, b1, acc[0][1], 0, 0, 0);
            acc[1][0] = __builtin_amdgcn_mfma_f32_16x16x32_f16(ah1, b0, acc[1][0], 0, 0, 0);
            acc[1][1] = __builtin_amdgcn_mfma_f32_16x16x32_f16(ah1, b1, acc[1][1], 0, 0, 0);
            acc[0][0] = __builtin_amdgcn_mfma_f32_16x16x32_f16(al0, b0, acc[0][0], 0, 0, 0);
            acc[0][1] = __builtin_amdgcn_mfma_f32_16x16x32_f16(al0, b1, acc[0][1], 0, 0, 0);
            acc[1][0] = __builtin_amdgcn_mfma_f32_16x16x32_f16(al1, b0, acc[1][0], 0, 0, 0);
            acc[1][1] = __builtin_amdgcn_mfma_f32_16x16x32_f16(al1, b1, acc[1][1], 0, 0, 0);
        }
    };

    STAGE(0, 0);
    STAGE(1, 1);
#pragma unroll 1
    for (int t = 0; t < 8; ++t) {
        if (t < 6) {
            STAGE((t + 2) % 3, t + 2);                     // keep 18 loads in flight
            asm volatile("s_waitcnt vmcnt(12)" ::: "memory");  // tile t landed; t+1,t+2 in flight
        } else if (t == 6) {
            asm volatile("s_waitcnt vmcnt(6)" ::: "memory");
        } else {
            asm volatile("s_waitcnt vmcnt(0)" ::: "memory");
        }
        __builtin_amdgcn_s_barrier();
        COMPUTE(t % 3);
        __builtin_amdgcn_s_barrier();   // all waves done reading before buf reuse
    }

    // C/D layout (m89-verified): col = lane&15, row = (lane>>4)*4 + reg
    const int crow = (lane >> 4) * 4, ccol = lane & 15;
#pragma unroll
    for (int f = 0; f < 2; ++f)
#pragma unroll
        for (int g = 0; g < 2; ++g) {
            int col = n0 + wn + g * 16 + ccol;
            float bv = bias[col];
#pragma unroll
            for (int r = 0; r < 4; ++r) {
                size_t row = m0 + wm + f * 16 + crow + r;
                float val = fast_tanh(acc[f][g][r] + bv);
                if (!isQ) P[row * H_DIM + col] = val;
                else      P[((size_t)(row & 7) * T_DIM + (row >> 3)) * H_DIM + col] = val;  // [b][t][h]
            }
        }
}

// scores[b][t][s] = sum_h v[h] * (tq+tk)/(1+tq*tk)
// lane = t (T==64); wave owns 2 adjacent s; block = 4 waves (8 s), one b.
// q from XOR-swizzled LDS tile [t][h-chunk] (conflict-free b128); k rows + v staged, broadcast.
__global__ __launch_bounds__(256) void scores_kernel(
    const float* __restrict__ tk, const float* __restrict__ tq2,
    const float* __restrict__ v, float* __restrict__ scores)
{
    __shared__ float kt[8][H_DIM];                 // 8 KB
    __shared__ float vs[H_DIM];                    // 1 KB
    __shared__ __align__(16) char qts[64 * 256];   // 16 KB: [t][64 h f32], XOR-swizzled
    __shared__ float ot[64][8];                    // 2 KB output stage
    const int tid = threadIdx.x;
    const int lane = tid & 63;                     // = t
    const int wv = tid >> 6;
    const int b = blockIdx.y, sblk = blockIdx.x * 8;

    for (int j = tid; j < 512; j += 256) {         // kt: 8 rows x 64 float4
        int r = j >> 6, c = (j & 63) * 4;
        *(float4*)&kt[r][c] = *(const float4*)&tk[((size_t)(sblk + r) * B_DIM + b) * H_DIM + c];
    }
    if (tid < 64) *(float4*)&vs[tid * 4] = ((const float4*)v)[tid];

    float acc0 = 0.f, acc1 = 0.f;
    const int r0 = wv * 2, r1 = wv * 2 + 1;

    for (int h0 = 0; h0 < H_DIM; h0 += 64) {
        __syncthreads();                            // protect qts reuse (and cover kt/vs 1st iter)
        for (int j = tid; j < 1024; j += 256) {     // qt[t][0..63] <- tq2[b][t][h0..h0+63]
            int t = j >> 4, hb = (j & 15) * 16;
            *(float4*)&qts[(t << 8) + (hb ^ ((t & 7) << 4))] =
                *(const float4*)&tq2[((size_t)b * T_DIM + t) * H_DIM + h0 + (hb >> 2)];
        }
        __syncthreads();
#pragma unroll
        for (int hq = 0; hq < 64; hq += 4) {
            float4 q  = *(const float4*)&qts[(lane << 8) + (((hq * 4)) ^ ((lane & 7) << 4))];
            float4 ka = *(const float4*)&kt[r0][h0 + hq];
            float4 kb = *(const float4*)&kt[r1][h0 + hq];
            float4 vv = *(const float4*)&vs[h0 + hq];
            acc0 = fmaf((q.x + ka.x) * vv.x, fast_rcp(fmaf(q.x, ka.x, 1.f)), acc0);
            acc0 = fmaf((q.y + ka.y) * vv.y, fast_rcp(fmaf(q.y, ka.y, 1.f)), acc0);
            acc0 = fmaf((q.z + ka.z) * vv.z, fast_rcp(fmaf(q.z, ka.z, 1.f)), acc0);
            acc0 = fmaf((q.w + ka.w) * vv.w, fast_rcp(fmaf(q.w, ka.w, 1.f)), acc0);
            acc1 = fmaf((q.x + kb.x) * vv.x, fast_rcp(fmaf(q.x, kb.x, 1.f)), acc1);
            acc1 = fmaf((q.y + kb.y) * vv.y, fast_rcp(fmaf(q.y, kb.y, 1.f)), acc1);
            acc1 = fmaf((q.z + kb.z) * vv.z, fast_rcp(fmaf(q.z, kb.z, 1.f)), acc1);
            acc1 = fmaf((q.w + kb.w) * vv.w, fast_rcp(fmaf(q.w, kb.w, 1.f)), acc1);
        }
    }
    ot[lane][r0] = acc0;
    ot[lane][r1] = acc1;
    __syncthreads();
    if (tid < 128) {                                // coalesced-ish 32B per t-row
        int t = tid >> 1, part = (tid & 1) * 4;
        *(float4*)&scores[((size_t)b * T_DIM + t) * S_DIM + sblk + part] = *(float4*)&ot[t][part];
    }
}

// row softmax over S=1024; one block per (b,t) row; 256 thr * float4
__global__ __launch_bounds__(256) void softmax_kernel(
    const float* __restrict__ scores, float* __restrict__ out)
{
    const int row = blockIdx.x;          // b*T + t
    const int lane = threadIdx.x & 63;
    const int wave = threadIdx.x >> 6;
    __shared__ float red[8];

    float4 x = ((const float4*)(scores + (size_t)row * S_DIM))[threadIdx.x];
    float m = fmaxf(fmaxf(x.x, x.y), fmaxf(x.z, x.w));
#pragma unroll
    for (int mm = 32; mm >= 1; mm >>= 1) m = fmaxf(m, __shfl_xor(m, mm, 64));
    if (lane == 0) red[wave] = m;
    __syncthreads();
    m = fmaxf(fmaxf(red[0], red[1]), fmaxf(red[2], red[3]));

    float e0 = __expf(x.x - m), e1 = __expf(x.y - m);
    float e2 = __expf(x.z - m), e3 = __expf(x.w - m);
    float sum = e0 + e1 + e2 + e3;
#pragma unroll
    for (int mm = 32; mm >= 1; mm >>= 1) sum += __shfl_xor(sum, mm, 64);
    if (lane == 0) red[4 + wave] = sum;
    __syncthreads();
    float inv = fast_rcp(red[4] + red[5] + red[6] + red[7]);

    float4 o;
    o.x = e0 * inv; o.y = e1 * inv; o.z = e2 * inv; o.w = e3 * inv;
    ((float4*)(out + (size_t)row * S_DIM))[threadIdx.x] = o;
}

extern "C" void kernel_launch(void* const* d_in, const int* in_sizes, int n_in,
                              void* d_out, int out_size, void* d_ws, size_t ws_size,
                              hipStream_t stream)
{
    const float* key   = (const float*)d_in[0];
    const float* query = (const float*)d_in[1];
    const float* Wk    = (const float*)d_in[2];
    const float* bk    = (const float*)d_in[3];
    const float* Wq    = (const float*)d_in[4];
    const float* bq    = (const float*)d_in[5];
    const float* v     = (const float*)d_in[6];
    float* out = (float*)d_out;

    float* tk     = (float*)d_ws;                       // S*B*H f32      (8.39 MB)
    float* tq2    = tk + (size_t)S_DIM * B_DIM * H_DIM; // B*T*H f32      (0.52 MB)
    float* scores = tq2 + (size_t)B_DIM * T_DIM * H_DIM;// B*T*S f32      (2.10 MB)
    f16* Khi = (f16*)(scores + (size_t)B_DIM * T_DIM * S_DIM);
    f16* Klo = Khi + (size_t)S_DIM * B_DIM * K_DIM;
    f16* Qhi = Klo + (size_t)S_DIM * B_DIM * K_DIM;
    f16* Qlo = Qhi + (size_t)T_DIM * B_DIM * K_DIM;
    f16* WTk = Qlo + (size_t)T_DIM * B_DIM * K_DIM;
    f16* WTq = WTk + (size_t)H_DIM * K_DIM;

    convert_all<<<2368, 256, 0, stream>>>(key, query, Wk, Wq, Khi, Klo, Qhi, Qlo, WTk, WTq);
    proj_gemm_all<<<544, 256, 0, stream>>>(Khi, Klo, WTk, bk, tk, Qhi, Qlo, WTq, bq, tq2);
    scores_kernel<<<dim3(S_DIM / 8, B_DIM), 256, 0, stream>>>(tk, tq2, v, scores);
    softmax_kernel<<<dim3(B_DIM * T_DIM), 256, 0, stream>>>(scores, out);
}

// Round 7
// 53.581 us; speedup vs baseline: 1.1106x; 1.1106x over previous
//
#include <hip/hip_runtime.h>

#define S_DIM 1024
#define T_DIM 64
#define B_DIM 8
#define K_DIM 512   // KEY_DIM == QUERY_DIM
#define H_DIM 256

typedef _Float16 f16;
typedef __attribute__((ext_vector_type(4))) _Float16 f16x4;
typedef __attribute__((ext_vector_type(8))) _Float16 f16x8;
typedef __attribute__((ext_vector_type(4))) float f32x4;

__device__ __forceinline__ float fast_rcp(float x) { return __builtin_amdgcn_rcpf(x); }

// tanh(x) = 1 - 2/(e^{2x}+1); robust for all x (rcp(inf)=0)
__device__ __forceinline__ float fast_tanh(float x) {
    float e = __expf(2.0f * x);
    return 1.0f - 2.0f * fast_rcp(e + 1.0f);
}

__device__ __forceinline__ void gload16(const void* g, void* l) {
    __builtin_amdgcn_global_load_lds(
        (const __attribute__((address_space(1))) unsigned int*)g,
        (__attribute__((address_space(3))) unsigned int*)l, 16, 0, 0);
}

// W transpose+convert only: Wk/Wq [K][H] f32 -> WT [H][K] f16  (1 MB total)
__global__ __launch_bounds__(256) void wconv_kernel(
    const float* __restrict__ Wk, const float* __restrict__ Wq,
    f16* __restrict__ WTk, f16* __restrict__ WTq)
{
    __shared__ float tile[64][65];
    const int idx = blockIdx.x;            // 64 blocks: 2 mats x 32 tiles
    const float* W = (idx & 32) ? Wq : Wk;
    f16* WT = (idx & 32) ? WTq : WTk;
    const int t32 = idx & 31;
    const int k0 = (t32 >> 2) * 64, n0 = (t32 & 3) * 64;
    const int c = threadIdx.x & 63, r0 = threadIdx.x >> 6;
#pragma unroll
    for (int i = 0; i < 16; ++i) {
        int r = r0 + i * 4;
        tile[r][c] = W[(size_t)(k0 + r) * H_DIM + n0 + c];
    }
    __syncthreads();
#pragma unroll
    for (int i = 0; i < 16; ++i) {
        int r = r0 + i * 4;
        WT[(size_t)(n0 + r) * K_DIM + k0 + c] = (f16)tile[c][r];
    }
}

// P = tanh(A @ W + bias).  A read as f32, split to fp16 hi/lo IN-KERNEL
// (reg-stage: global->reg->convert->swizzled ds_write).  W as f16 BT[N][K] via
// global_load_lds (linear dest, pre-swizzled source).  64x64 tile, BK=64,
// 4 waves (2x2).  One barrier per k-step; next tile's loads issued before
// COMPUTE so HBM latency hides under MFMA (T14).
// bid<512: key (write tk[m][h]); else query (write tq2[b][t][h]).
__global__ __launch_bounds__(256, 3) void proj_gemm_all(
    const float* __restrict__ key, const f16* __restrict__ WTk,
    const float* __restrict__ bk, float* __restrict__ tk,
    const float* __restrict__ query, const f16* __restrict__ WTq,
    const float* __restrict__ bq, float* __restrict__ tq2)
{
    __shared__ __align__(16) char smem[2][3][8192];   // [buf][Ahi,Alo,B][64 rows x 128 B]
    const int tid = threadIdx.x;
    const int lane = tid & 63, wid = tid >> 6;
    const int widu = __builtin_amdgcn_readfirstlane(wid);
    const int wm = (wid >> 1) * 32, wn = (wid & 1) * 32;

    // XCD swizzle (bijective: 544 = 8*68): 4 sibling n-blocks of one A-panel -> same XCD L2
    const int bid0 = blockIdx.x;
    const int bid = (bid0 & 7) * 68 + (bid0 >> 3);
    const bool isQ = bid >= 512;
    const int lb = isQ ? bid - 512 : bid;
    const size_t m0 = (size_t)(lb >> 2) * 64;
    const int n0 = (lb & 3) * 64;
    const float* A   = isQ ? query : key;
    const f16* BT    = isQ ? WTq : WTk;
    const float* bias = isQ ? bq : bk;
    float* P = isQ ? tq2 : tk;

    // ---- B staging via global_load_lds (swizzled source, linear dest) ----
    const int o0 = wid * 1024 + (lane << 4);
    const int o1 = o0 + 4096;
    const int row0 = o0 >> 7, kb0 = (o0 & 127) ^ ((row0 & 7) << 4);
    const int row1 = o1 >> 7, kb1 = (o1 & 127) ^ ((row1 & 7) << 4);
    const char* b_t = (const char*)(BT + (size_t)n0 * K_DIM);   // row stride 1024 B

    auto GLOADB = [&](int buf, int t) {
        const int kb = t * 128;
        char* d0 = &smem[buf][2][widu * 1024];
        gload16(b_t + (size_t)row0 * 1024 + kb + kb0, d0);
        gload16(b_t + (size_t)row1 * 1024 + kb + kb1, d0 + 4096);
    };

    // ---- A staging: global f32 -> regs -> fp16 hi/lo -> swizzled ds_write ----
    const float* a_base = A + m0 * K_DIM;
    float4 areg[4];
    auto ALOAD = [&](int t) {
#pragma unroll
        for (int j = 0; j < 4; ++j) {
            const int fidx = j * 256 + tid;
            const int r = fidx >> 4, c16 = fidx & 15;
            areg[j] = *(const float4*)&a_base[(size_t)r * K_DIM + t * 64 + c16 * 4];
        }
    };
    auto AWRITE = [&](int buf) {
#pragma unroll
        for (int j = 0; j < 4; ++j) {
            const int fidx = j * 256 + tid;
            const int r = fidx >> 4, c16 = fidx & 15;
            const int byt = r * 128 + ((c16 * 8) ^ ((r & 7) << 4));
            f16 h0 = (f16)areg[j].x, h1 = (f16)areg[j].y, h2 = (f16)areg[j].z, h3 = (f16)areg[j].w;
            f16x4 hi = {h0, h1, h2, h3};
            f16x4 lo = {(f16)(areg[j].x - (float)h0), (f16)(areg[j].y - (float)h1),
                        (f16)(areg[j].z - (float)h2), (f16)(areg[j].w - (float)h3)};
            *(f16x4*)&smem[buf][0][byt] = hi;
            *(f16x4*)&smem[buf][1][byt] = lo;
        }
    };

    f32x4 acc[2][2] = {};
    const int fr = lane & 15, fgb = (lane >> 4) << 4;

    auto COMPUTE = [&](int buf) {
#pragma unroll
        for (int kk = 0; kk < 2; ++kk) {
            const int kbyte = kk * 64 + fgb;
            auto ld = [&](int arr, int row) -> f16x8 {
                int byt = ((row << 7) + kbyte) ^ ((row & 7) << 4);
                return *(const f16x8*)&smem[buf][arr][byt];
            };
            f16x8 ah0 = ld(0, wm + fr),      ah1 = ld(0, wm + 16 + fr);
            f16x8 al0 = ld(1, wm + fr),      al1 = ld(1, wm + 16 + fr);
            f16x8 b0  = ld(2, wn + fr),      b1  = ld(2, wn + 16 + fr);
            acc[0][0] = __builtin_amdgcn_mfma_f32_16x16x32_f16(ah0, b0, acc[0][0], 0, 0, 0);
            acc[0][1] = __builtin_amdgcn_mfma_f32_16x16x32_f16(ah0, b1, acc[0][1], 0, 0, 0);
            acc[1][0] = __builtin_amdgcn_mfma_f32_16x16x32_f16(ah1, b0, acc[1][0], 0, 0, 0);
            acc[1][1] = __builtin_amdgcn_mfma_f32_16x16x32_f16(ah1, b1, acc[1][1], 0, 0, 0);
            acc[0][0] = __builtin_amdgcn_mfma_f32_16x16x32_f16(al0, b0, acc[0][0], 0, 0, 0);
            acc[0][1] = __builtin_amdgcn_mfma_f32_16x16x32_f16(al0, b1, acc[0][1], 0, 0, 0);
            acc[1][0] = __builtin_amdgcn_mfma_f32_16x16x32_f16(al1, b0, acc[1][0], 0, 0, 0);
            acc[1][1] = __builtin_amdgcn_mfma_f32_16x16x32_f16(al1, b1, acc[1][1], 0, 0, 0);
        }
    };

    // prologue: tile 0
    ALOAD(0);
    GLOADB(0, 0);
    AWRITE(0);            // compiler waits on areg use; barrier drains gload
    __syncthreads();

    int buf = 0;
#pragma unroll 1
    for (int t = 0; t < 8; ++t) {
        if (t < 7) {
            ALOAD(t + 1);             // issue next-tile loads BEFORE compute (latency hides)
            GLOADB(buf ^ 1, t + 1);
        }
        COMPUTE(buf);
        if (t < 7) {
            AWRITE(buf ^ 1);          // implicit vmcnt wait on areg here, after MFMA issue
            __syncthreads();          // drains gloadB(buf^1); protects buf reuse
        }
        buf ^= 1;
    }

    // C/D layout (m89-verified): col = lane&15, row = (lane>>4)*4 + reg
    const int crow = (lane >> 4) * 4, ccol = lane & 15;
#pragma unroll
    for (int f = 0; f < 2; ++f)
#pragma unroll
        for (int g = 0; g < 2; ++g) {
            int col = n0 + wn + g * 16 + ccol;
            float bv = bias[col];
#pragma unroll
            for (int r = 0; r < 4; ++r) {
                size_t row = m0 + wm + f * 16 + crow + r;
                float val = fast_tanh(acc[f][g][r] + bv);
                if (!isQ) P[row * H_DIM + col] = val;
                else      P[((size_t)(row & 7) * T_DIM + (row >> 3)) * H_DIM + col] = val;  // [b][t][h]
            }
        }
}

// scores[b][t][s] = sum_h v[h] * (tq+tk)/(1+tq*tk)
// lane = t (T==64); wave owns 2 adjacent s; block = 4 waves (8 s), one b.
__global__ __launch_bounds__(256) void scores_kernel(
    const float* __restrict__ tk, const float* __restrict__ tq2,
    const float* __restrict__ v, float* __restrict__ scores)
{
    __shared__ float kt[8][H_DIM];                 // 8 KB
    __shared__ float vs[H_DIM];                    // 1 KB
    __shared__ __align__(16) char qts[64 * 256];   // 16 KB: [t][64 h f32], XOR-swizzled
    __shared__ float ot[64][8];                    // 2 KB output stage
    const int tid = threadIdx.x;
    const int lane = tid & 63;                     // = t
    const int wv = tid >> 6;
    const int b = blockIdx.y, sblk = blockIdx.x * 8;

    for (int j = tid; j < 512; j += 256) {         // kt: 8 rows x 64 float4
        int r = j >> 6, c = (j & 63) * 4;
        *(float4*)&kt[r][c] = *(const float4*)&tk[((size_t)(sblk + r) * B_DIM + b) * H_DIM + c];
    }
    if (tid < 64) *(float4*)&vs[tid * 4] = ((const float4*)v)[tid];

    float acc0 = 0.f, acc1 = 0.f;
    const int r0 = wv * 2, r1 = wv * 2 + 1;

    for (int h0 = 0; h0 < H_DIM; h0 += 64) {
        __syncthreads();                            // protect qts reuse (and cover kt/vs 1st iter)
        for (int j = tid; j < 1024; j += 256) {     // qt[t][0..63] <- tq2[b][t][h0..h0+63]
            int t = j >> 4, hb = (j & 15) * 16;
            *(float4*)&qts[(t << 8) + (hb ^ ((t & 7) << 4))] =
                *(const float4*)&tq2[((size_t)b * T_DIM + t) * H_DIM + h0 + (hb >> 2)];
        }
        __syncthreads();
#pragma unroll
        for (int hq = 0; hq < 64; hq += 4) {
            float4 q  = *(const float4*)&qts[(lane << 8) + (((hq * 4)) ^ ((lane & 7) << 4))];
            float4 ka = *(const float4*)&kt[r0][h0 + hq];
            float4 kb = *(const float4*)&kt[r1][h0 + hq];
            float4 vv = *(const float4*)&vs[h0 + hq];
            acc0 = fmaf((q.x + ka.x) * vv.x, fast_rcp(fmaf(q.x, ka.x, 1.f)), acc0);
            acc0 = fmaf((q.y + ka.y) * vv.y, fast_rcp(fmaf(q.y, ka.y, 1.f)), acc0);
            acc0 = fmaf((q.z + ka.z) * vv.z, fast_rcp(fmaf(q.z, ka.z, 1.f)), acc0);
            acc0 = fmaf((q.w + ka.w) * vv.w, fast_rcp(fmaf(q.w, ka.w, 1.f)), acc0);
            acc1 = fmaf((q.x + kb.x) * vv.x, fast_rcp(fmaf(q.x, kb.x, 1.f)), acc1);
            acc1 = fmaf((q.y + kb.y) * vv.y, fast_rcp(fmaf(q.y, kb.y, 1.f)), acc1);
            acc1 = fmaf((q.z + kb.z) * vv.z, fast_rcp(fmaf(q.z, kb.z, 1.f)), acc1);
            acc1 = fmaf((q.w + kb.w) * vv.w, fast_rcp(fmaf(q.w, kb.w, 1.f)), acc1);
        }
    }
    ot[lane][r0] = acc0;
    ot[lane][r1] = acc1;
    __syncthreads();
    if (tid < 128) {                                // coalesced-ish 32B per t-row
        int t = tid >> 1, part = (tid & 1) * 4;
        *(float4*)&scores[((size_t)b * T_DIM + t) * S_DIM + sblk + part] = *(float4*)&ot[t][part];
    }
}

// row softmax over S=1024; one block per (b,t) row; 256 thr * float4
__global__ __launch_bounds__(256) void softmax_kernel(
    const float* __restrict__ scores, float* __restrict__ out)
{
    const int row = blockIdx.x;          // b*T + t
    const int lane = threadIdx.x & 63;
    const int wave = threadIdx.x >> 6;
    __shared__ float red[8];

    float4 x = ((const float4*)(scores + (size_t)row * S_DIM))[threadIdx.x];
    float m = fmaxf(fmaxf(x.x, x.y), fmaxf(x.z, x.w));
#pragma unroll
    for (int mm = 32; mm >= 1; mm >>= 1) m = fmaxf(m, __shfl_xor(m, mm, 64));
    if (lane == 0) red[wave] = m;
    __syncthreads();
    m = fmaxf(fmaxf(red[0], red[1]), fmaxf(red[2], red[3]));

    float e0 = __expf(x.x - m), e1 = __expf(x.y - m);
    float e2 = __expf(x.z - m), e3 = __expf(x.w - m);
    float sum = e0 + e1 + e2 + e3;
#pragma unroll
    for (int mm = 32; mm >= 1; mm >>= 1) sum += __shfl_xor(sum, mm, 64);
    if (lane == 0) red[4 + wave] = sum;
    __syncthreads();
    float inv = fast_rcp(red[4] + red[5] + red[6] + red[7]);

    float4 o;
    o.x = e0 * inv; o.y = e1 * inv; o.z = e2 * inv; o.w = e3 * inv;
    ((float4*)(out + (size_t)row * S_DIM))[threadIdx.x] = o;
}

extern "C" void kernel_launch(void* const* d_in, const int* in_sizes, int n_in,
                              void* d_out, int out_size, void* d_ws, size_t ws_size,
                              hipStream_t stream)
{
    const float* key   = (const float*)d_in[0];
    const float* query = (const float*)d_in[1];
    const float* Wk    = (const float*)d_in[2];
    const float* bk    = (const float*)d_in[3];
    const float* Wq    = (const float*)d_in[4];
    const float* bq    = (const float*)d_in[5];
    const float* v     = (const float*)d_in[6];
    float* out = (float*)d_out;

    float* tk     = (float*)d_ws;                       // S*B*H f32      (8.39 MB)
    float* tq2    = tk + (size_t)S_DIM * B_DIM * H_DIM; // B*T*H f32      (0.52 MB)
    float* scores = tq2 + (size_t)B_DIM * T_DIM * H_DIM;// B*T*S f32      (2.10 MB)
    f16* WTk = (f16*)(scores + (size_t)B_DIM * T_DIM * S_DIM);  // H*K f16 (0.26 MB)
    f16* WTq = WTk + (size_t)H_DIM * K_DIM;                     // H*K f16 (0.26 MB)

    wconv_kernel<<<64, 256, 0, stream>>>(Wk, Wq, WTk, WTq);
    proj_gemm_all<<<544, 256, 0, stream>>>(key, WTk, bk, tk, query, WTq, bq, tq2);
    scores_kernel<<<dim3(S_DIM / 8, B_DIM), 256, 0, stream>>>(tk, tq2, v, scores);
    softmax_kernel<<<dim3(B_DIM * T_DIM), 256, 0, stream>>>(scores, out);
}